// Round 7
// baseline (186.233 us; speedup 1.0000x reference)
//
#include <hip/hip_runtime.h>
#include <cstdint>
#include <cstddef>

#define N_NODES 8192
#define N_EDGES 131072
#define F_IN    512
#define H1C     32
#define H2C     16

// ---------------- helpers ----------------

__device__ __forceinline__ float block_reduce_sum(float v, int nthreads) {
    #pragma unroll
    for (int off = 32; off; off >>= 1) v += __shfl_down(v, off, 64);
    __shared__ float sred[16];
    int lane = threadIdx.x & 63, wid = threadIdx.x >> 6;
    if (lane == 0) sred[wid] = v;
    __syncthreads();
    float s = 0.0f;
    if (threadIdx.x == 0) {
        int nw = nthreads >> 6;
        for (int i = 0; i < nw; ++i) s += sred[i];
    }
    return s;
}

// POS_WEIGHT=10: y=1 -> 10*softplus(-l); y=0 -> softplus(l).
// Branch-free: sp(l) = lse + relu(l);  val = sp(l)*(1+9y) - 10*y*l
__device__ __forceinline__ float bce_elem(float l, int y) {
    float lse = __logf(1.0f + __expf(-fabsf(l)));
    float sp  = lse + fmaxf(l, 0.0f);
    float w   = (float)y;
    return fmaf(sp, fmaf(9.0f, w, 1.0f), -10.0f * w * l);
}

// ---------------- kernels ----------------

// zero deg (2048 f4) + agg1 (65536 f4) + aggmu/agglv (65536 f4, contiguous)
__global__ void k_init(float4* __restrict__ deg4, float4* __restrict__ agg14,
                       float4* __restrict__ aggmu4) {
    int gid = blockIdx.x * 256 + threadIdx.x;
    float4 zz = {0.0f, 0.0f, 0.0f, 0.0f};
    if (gid < 2048) deg4[gid] = zz;
    else if (gid < 2048 + 65536) agg14[gid - 2048] = zz;
    else aggmu4[gid - 67584] = zz;
}

__global__ void k_deg(const int* __restrict__ dst, int* __restrict__ deg) {
    int e = blockIdx.x * 256 + threadIdx.x;
    if (e < N_EDGES) atomicAdd(&deg[dst[e]], 1);
}

// h = x @ W1 : [8192,512] x [512,32], 32-row tiles (256 blocks -> all CUs)
__global__ void k_gemm1(const float* __restrict__ x, const float* __restrict__ W1,
                        float* __restrict__ h) {
    __shared__ float xs[32][33];
    __shared__ float wsm[32][32];
    int tid = threadIdx.x;
    int tc = tid & 7;        // col quad
    int tr = tid >> 3;       // row 0..31
    int rowbase = blockIdx.x * 32;

    float ax = 0.f, ay = 0.f, az = 0.f, aw = 0.f;

    for (int kc = 0; kc < F_IN / 32; ++kc) {
        __syncthreads();
        {
            int pos = tc << 2;
            float4 v = *(const float4*)&x[(size_t)(rowbase + tr) * F_IN + kc * 32 + pos];
            xs[tr][pos + 0] = v.x; xs[tr][pos + 1] = v.y;
            xs[tr][pos + 2] = v.z; xs[tr][pos + 3] = v.w;
            *(float4*)&wsm[tr][pos] = *(const float4*)&W1[(size_t)(kc * 32 + tr) * H1C + pos];
        }
        __syncthreads();
        #pragma unroll
        for (int k = 0; k < 32; ++k) {
            float4 wv = *(const float4*)&wsm[k][tc << 2];
            float xv = xs[tr][k];
            ax += xv * wv.x; ay += xv * wv.y; az += xv * wv.z; aw += xv * wv.w;
        }
    }
    float4 v; v.x = ax; v.y = ay; v.z = az; v.w = aw;
    *(float4*)&h[(size_t)(rowbase + tr) * H1C + (tc << 2)] = v;
}

// scatter layer1: agg1[dst] += h[src] * rsqrt((deg_s+1)(deg_d+1))
__global__ void k_scatter1(const int* __restrict__ src, const int* __restrict__ dst,
                           const float* __restrict__ h, const int* __restrict__ deg,
                           float* __restrict__ agg1) {
    int gid = blockIdx.x * 256 + threadIdx.x;
    int e = gid >> 5, f = gid & 31;
    int s = src[e], d = dst[e];
    float c = rsqrtf((float)((deg[s] + 1) * (deg[d] + 1)));
    unsafeAtomicAdd(&agg1[(d << 5) + f], h[(s << 5) + f] * c);
}

// fused: h1 = relu(agg1 + h/(deg+1)) built in LDS, then h1@W2 and h1@W3
__global__ void k_gemm2(const float* __restrict__ agg1, const float* __restrict__ h,
                        const int* __restrict__ deg, const float* __restrict__ W2,
                        const float* __restrict__ W3, float* __restrict__ h2mu,
                        float* __restrict__ h2lv) {
    __shared__ float h1s[8][33];
    __shared__ float w2s[H1C * H2C], w3s[H1C * H2C];
    int tid = threadIdx.x;
    int rb = blockIdx.x * 8;
    for (int i = tid; i < H1C * H2C; i += 256) { w2s[i] = W2[i]; w3s[i] = W3[i]; }
    {
        int r = tid >> 5, c = tid & 31;
        int row = rb + r;
        float d2 = 1.0f / (float)(deg[row] + 1);
        h1s[r][c] = fmaxf(fmaf(h[(row << 5) + c], d2, agg1[(row << 5) + c]), 0.0f);
    }
    __syncthreads();
    int r = tid >> 5, cc = tid & 31, col = cc & 15;
    const float* wsrc = (cc & 16) ? w3s : w2s;
    float acc = 0.0f;
    #pragma unroll
    for (int k = 0; k < H1C; ++k) acc += h1s[r][k] * wsrc[(k << 4) + col];
    int row = rb + r;
    if (cc & 16) h2lv[(row << 4) + col] = acc;
    else         h2mu[(row << 4) + col] = acc;
}

// scatter layer2: both mu and logvar (16 lanes each per edge)
__global__ void k_scatter2(const int* __restrict__ src, const int* __restrict__ dst,
                           const float* __restrict__ h2mu, const float* __restrict__ h2lv,
                           const int* __restrict__ deg, float* __restrict__ aggmu,
                           float* __restrict__ agglv) {
    int gid = blockIdx.x * 256 + threadIdx.x;
    int e = gid >> 5, f = gid & 31;
    int s = src[e], d = dst[e];
    float c = rsqrtf((float)((deg[s] + 1) * (deg[d] + 1)));
    int ff = f & 15;
    if (f < 16) unsafeAtomicAdd(&aggmu[(d << 4) + ff], h2mu[(s << 4) + ff] * c);
    else        unsafeAtomicAdd(&agglv[(d << 4) + ff], h2lv[(s << 4) + ff] * c);
}

__global__ void k_zmu(const float* __restrict__ aggmu, const float* __restrict__ agglv,
                      const float* __restrict__ h2mu, const float* __restrict__ h2lv,
                      const int* __restrict__ deg, const float* __restrict__ eps,
                      float* __restrict__ zbuf, float* __restrict__ out,
                      float* __restrict__ kldp) {
    int gid = blockIdx.x * 256 + threadIdx.x;
    int row = gid >> 4;
    float d2 = 1.0f / (float)(deg[row] + 1);
    float m  = fmaf(h2mu[gid], d2, aggmu[gid]);
    float lv = fmaf(h2lv[gid], d2, agglv[gid]);
    float el = __expf(lv);
    float zv = fmaf(eps[gid], el, m);
    zbuf[gid] = zv;
    out[1 + gid] = m;
    float kt = 1.0f + 2.0f * lv - m * m - el * el;
    float bs = block_reduce_sum(kt, 256);
    if (threadIdx.x == 0) kldp[blockIdx.x] = bs;
}

// ---- BCE: 512 blocks, each owns 16 rows x all 8192 cols; 16 col-tiles of 512.
// adj is streamed sequentially per row in 1KB-per-wave bursts. zr (wave-uniform
// 4 rows of z) loaded from a readfirstlane'd base (scalar-load candidate).
// zc double-buffered in LDS, transposed [16][516]; A/B pipeline with named
// registers (no dynamic indexing -> no scratch).

#define STAGE_LOAD(t, z0, z1, z2, z3, y0, y1, y2, y3)                            \
    {                                                                            \
        const float4* zp_ = (const float4*)&z[(size_t)((t) * 512 + tid) * H2C];  \
        z0 = zp_[0]; z1 = zp_[1]; z2 = zp_[2]; z3 = zp_[3];                      \
        const int* ap_ = abase + (size_t)(t) * 512;                              \
        y0 = *(const int4*)(ap_);                                                \
        y1 = *(const int4*)(ap_ + N_NODES);                                      \
        y2 = *(const int4*)(ap_ + 2 * N_NODES);                                  \
        y3 = *(const int4*)(ap_ + 3 * N_NODES);                                  \
    }

#define STAGE_WRITE(ZC, z0, z1, z2, z3)                                          \
    {                                                                            \
        ZC[0][tid]  = z0.x; ZC[1][tid]  = z0.y;                                  \
        ZC[2][tid]  = z0.z; ZC[3][tid]  = z0.w;                                  \
        ZC[4][tid]  = z1.x; ZC[5][tid]  = z1.y;                                  \
        ZC[6][tid]  = z1.z; ZC[7][tid]  = z1.w;                                  \
        ZC[8][tid]  = z2.x; ZC[9][tid]  = z2.y;                                  \
        ZC[10][tid] = z2.z; ZC[11][tid] = z2.w;                                  \
        ZC[12][tid] = z3.x; ZC[13][tid] = z3.y;                                  \
        ZC[14][tid] = z3.z; ZC[15][tid] = z3.w;                                  \
    }

#define COMPUTE_TILE(ZC, y0, y1, y2, y3)                                         \
    {                                                                            \
        float a[4][4] = {{0.0f}};                                                \
        _Pragma("unroll")                                                        \
        for (int k = 0; k < 16; ++k) {                                           \
            float4 c4 = *(const float4*)&ZC[k][tx << 2];                         \
            _Pragma("unroll")                                                    \
            for (int r = 0; r < 4; ++r) {                                        \
                float zv = zr[r][k];                                             \
                a[r][0] += zv * c4.x; a[r][1] += zv * c4.y;                      \
                a[r][2] += zv * c4.z; a[r][3] += zv * c4.w;                      \
            }                                                                    \
        }                                                                        \
        lsum += bce_elem(a[0][0], y0.x) + bce_elem(a[0][1], y0.y)                \
              + bce_elem(a[0][2], y0.z) + bce_elem(a[0][3], y0.w);               \
        lsum += bce_elem(a[1][0], y1.x) + bce_elem(a[1][1], y1.y)                \
              + bce_elem(a[1][2], y1.z) + bce_elem(a[1][3], y1.w);               \
        lsum += bce_elem(a[2][0], y2.x) + bce_elem(a[2][1], y2.y)                \
              + bce_elem(a[2][2], y2.z) + bce_elem(a[2][3], y2.w);               \
        lsum += bce_elem(a[3][0], y3.x) + bce_elem(a[3][1], y3.y)                \
              + bce_elem(a[3][2], y3.z) + bce_elem(a[3][3], y3.w);               \
    }

__global__ void __launch_bounds__(512)
k_bce(const float* __restrict__ z, const int* __restrict__ adj,
      float* __restrict__ part) {
    __shared__ float zcA[16][516];
    __shared__ float zcB[16][516];
    int tid = threadIdx.x;
    int rbase = blockIdx.x << 4;           // 16 rows per block
    int tx = tid & 127, ty = tid >> 7;     // 128 col-groups x 4 row-groups

    // this wave's 4 z-rows are wave-uniform: readfirstlane'd base
    int tyu = __builtin_amdgcn_readfirstlane(ty);
    float zr[4][16];
    {
        const float* zp = &z[(size_t)(rbase + (tyu << 2)) * H2C];
        #pragma unroll
        for (int r = 0; r < 4; ++r)
            #pragma unroll
            for (int k = 0; k < 16; ++k) zr[r][k] = zp[r * 16 + k];
    }

    const int* abase = adj + (size_t)(rbase + (ty << 2)) * N_NODES + (tx << 2);

    float lsum = 0.0f;
    float4 zA0, zA1, zA2, zA3, zB0, zB1, zB2, zB3;
    int4 yA0, yA1, yA2, yA3, yB0, yB1, yB2, yB3;

    STAGE_LOAD(0, zA0, zA1, zA2, zA3, yA0, yA1, yA2, yA3);
    STAGE_WRITE(zcA, zA0, zA1, zA2, zA3);
    __syncthreads();

    #pragma unroll 1
    for (int it2 = 0; it2 < 8; ++it2) {
        STAGE_LOAD(2 * it2 + 1, zB0, zB1, zB2, zB3, yB0, yB1, yB2, yB3);
        COMPUTE_TILE(zcA, yA0, yA1, yA2, yA3);
        STAGE_WRITE(zcB, zB0, zB1, zB2, zB3);
        __syncthreads();
        if (it2 < 7) {
            STAGE_LOAD(2 * it2 + 2, zA0, zA1, zA2, zA3, yA0, yA1, yA2, yA3);
        }
        COMPUTE_TILE(zcB, yB0, yB1, yB2, yB3);
        if (it2 < 7) {
            STAGE_WRITE(zcA, zA0, zA1, zA2, zA3);
            __syncthreads();
        }
    }

    float bs = block_reduce_sum(lsum, 512);
    if (tid == 0) part[blockIdx.x] = bs;
}

__global__ void k_final(const float* __restrict__ part, const float* __restrict__ kldp,
                        const float* __restrict__ norm, float* __restrict__ out) {
    double s = 0.0, k = 0.0;
    for (int i = threadIdx.x; i < 512; i += 256) s += (double)part[i];
    for (int i = threadIdx.x; i < 512; i += 256) k += (double)kldp[i];
    #pragma unroll
    for (int off = 32; off; off >>= 1) {
        s += __shfl_down(s, off, 64);
        k += __shfl_down(k, off, 64);
    }
    __shared__ double ss[4], kk[4];
    int lane = threadIdx.x & 63, wid = threadIdx.x >> 6;
    if (lane == 0) { ss[wid] = s; kk[wid] = k; }
    __syncthreads();
    if (threadIdx.x == 0) {
        double st = ss[0] + ss[1] + ss[2] + ss[3];
        double kt = kk[0] + kk[1] + kk[2] + kk[3];
        double bce = st / ((double)N_NODES * (double)N_NODES);
        double kld = (-0.5 / (double)N_NODES) * (kt / (double)N_NODES);
        out[0] = (float)((double)norm[0] * bce + kld);
    }
}

// ---------------- launch ----------------

extern "C" void kernel_launch(void* const* d_in, const int* in_sizes, int n_in,
                              void* d_out, int out_size, void* d_ws, size_t ws_size,
                              hipStream_t stream) {
    const float* x    = (const float*)d_in[0];
    const int*   ei   = (const int*)d_in[1];
    const int*   adj  = (const int*)d_in[2];
    const float* eps  = (const float*)d_in[3];
    const float* norm = (const float*)d_in[4];
    const float* W1   = (const float*)d_in[5];
    const float* W2   = (const float*)d_in[6];
    const float* W3   = (const float*)d_in[7];
    float* out = (float*)d_out;
    char*  ws  = (char*)d_ws;

    const int* src = ei;
    const int* dst = ei + N_EDGES;

    int*   deg    = (int*)  (ws + 0);
    float* h      = (float*)(ws + 65536);
    float* agg1   = (float*)(ws + 1114112);
    float* h2mu   = (float*)(ws + 2162688);
    float* h2lv   = (float*)(ws + 2686976);
    float* aggmu  = (float*)(ws + 3211264);
    float* agglv  = (float*)(ws + 3735552);   // contiguous after aggmu
    float* zbuf   = (float*)(ws + 4259840);
    float* part   = (float*)(ws + 4784128);   // 512 f32
    float* kldp   = (float*)(ws + 4786176);   // 512 f32

    k_init<<<520, 256, 0, stream>>>((float4*)deg, (float4*)agg1, (float4*)aggmu);
    k_deg<<<N_EDGES / 256, 256, 0, stream>>>(dst, deg);
    k_gemm1<<<N_NODES / 32, 256, 0, stream>>>(x, W1, h);
    k_scatter1<<<(N_EDGES * 32) / 256, 256, 0, stream>>>(src, dst, h, deg, agg1);
    k_gemm2<<<N_NODES / 8, 256, 0, stream>>>(agg1, h, deg, W2, W3, h2mu, h2lv);
    k_scatter2<<<(N_EDGES * 32) / 256, 256, 0, stream>>>(src, dst, h2mu, h2lv, deg, aggmu, agglv);
    k_zmu<<<(N_NODES * H2C) / 256, 256, 0, stream>>>(aggmu, agglv, h2mu, h2lv, deg, eps, zbuf, out, kldp);
    k_bce<<<512, 512, 0, stream>>>(zbuf, adj, part);
    k_final<<<1, 256, 0, stream>>>(part, kldp, norm, out);
}